// Round 3
// baseline (1458.135 us; speedup 1.0000x reference)
//
#include <hip/hip_runtime.h>
#include <cstdint>

// ---------------------------------------------------------------------------
// MMoE: x[B,D] -> E experts (Linear D->H1, BN+ReLU, Linear H1->H2, BN+ReLU),
// T gates (softmax over E), out[t,b,e*H2+k] = expert[e,b,k]*gate[t,b,e].
// B=32768 D=1472 E=8 H1=512 H2=256 T=2.
//
// R5 structure (this round):
//  - gemm256: 256x256 tile, 512 thr / 8 waves (2M x 4N), per-wave 128x64.
//    8-phase k-slab schedule as R4, but with the CRITICAL fix:
//    R3/R4 used asm("s_barrier":::"memory") -> LLVM marks it mayLoad/mayStore
//    -> SIInsertWaitcnts drains vmcnt(0) before EVERY phase barrier -> the
//    counted-vmcnt pipeline silently degenerated to drain-per-phase (m218-V1,
//    == 1-phase perf).  Now: __builtin_amdgcn_s_barrier() (no memory
//    semantics, no forced drain) + BARE asm volatile s_waitcnt (no clobber) +
//    sched_barrier(0) after each slab-boundary cluster to pin ds_reads
//    (rule #18 fence).  Loads for slab u+2 stay in flight across barriers.
//    Ledger: slot (u+2)&3 last read in slab u-2 (reads retired before that
//    slab's trailing barriers via compiler lgkmcnt before MFMA); staged in
//    slab u >= 2 barriers later -> WAR-safe.  vmcnt(4) at slab end retires
//    slab u+1's 4 loads/thread (u+2's 4 stay outstanding); vmcnt(0) only
//    before the last prefetched slab.
//    LDS XOR swizzle byte^=(((row>>1)&3)<<4) via pre-swizzled global source
//    (global_load_lds writes linearly) + swizzled ds_read (0 conflicts, R3).
//    Column sum/sumsq fused in epilogue (BN stats).
//  - MFMA accumulation order per acc element identical to R3/R4 -> bitwise-same.
//  - Gates: tiny MFMA kernel from x_b (L3-resident).  h1 is [B][4096];
//    GEMM2 reads expert slice in place (lda=4096), one N-tile per expert.
//  - Biases b1/b2 cancel exactly through BatchNorm -> skipped.
// ---------------------------------------------------------------------------

typedef __attribute__((ext_vector_type(8))) __bf16 bf16x8;
typedef __attribute__((ext_vector_type(4))) float f32x4;

__device__ __forceinline__ unsigned short f2bf(float f) {
  unsigned int u = __float_as_uint(f);
  u += 0x7fffu + ((u >> 16) & 1u);   // round-to-nearest-even
  return (unsigned short)(u >> 16);
}

// async global->LDS, 16B per lane.  LDS dest must be wave-uniform base + lane*16.
__device__ __forceinline__ void async16(const void* g, void* l) {
  __builtin_amdgcn_global_load_lds((__attribute__((address_space(1))) unsigned int*)g,
                                   (__attribute__((address_space(3))) unsigned int*)l,
                                   16, 0, 0);
}

// ---------------- fp32 -> bf16 elementwise convert (x) ----------------------
__global__ void convert_f32_bf16(const float* __restrict__ in,
                                 unsigned short* __restrict__ out, size_t n) {
  size_t i = ((size_t)blockIdx.x * blockDim.x + threadIdx.x) * 4;
  if (i + 3 < n) {
    float4 v = *(const float4*)(in + i);
    unsigned int w0 = (unsigned int)f2bf(v.x) | ((unsigned int)f2bf(v.y) << 16);
    unsigned int w1 = (unsigned int)f2bf(v.z) | ((unsigned int)f2bf(v.w) << 16);
    *(uint2*)(out + i) = make_uint2(w0, w1);
  }
}

// ---------------- W[E][D][H] fp32 -> Wt rows [e*H+h][D] bf16 ----------------
__global__ void transpose_bf16(const float* __restrict__ W,
                               unsigned short* __restrict__ Wt, int D, int H) {
  __shared__ float tile[32][33];
  int e = blockIdx.z;
  int d0 = blockIdx.x * 32, h0 = blockIdx.y * 32;
  const float* We = W + (size_t)e * D * H;
  unsigned short* Wte = Wt + (size_t)e * D * H;
  int tx = threadIdx.x, ty = threadIdx.y;  // block (32,8)
#pragma unroll
  for (int i = 0; i < 4; ++i)
    tile[ty + i * 8][tx] = We[(size_t)(d0 + ty + i * 8) * H + h0 + tx];
  __syncthreads();
#pragma unroll
  for (int i = 0; i < 4; ++i)
    Wte[(size_t)(h0 + ty + i * 8) * D + d0 + tx] = f2bf(tile[tx][ty + i * 8]);
}

// ---------------- Wg[T][D][E] fp32 -> rows [t*8+e][D] bf16 ------------------
__global__ void transpose_wg(const float* __restrict__ Wg,
                             unsigned short* __restrict__ Wt, int D) {
  int idx = blockIdx.x * 256 + threadIdx.x;            // 16*D total
  int te = idx / D, d = idx - te * D;
  int t = te >> 3, e = te & 7;
  Wt[(size_t)te * D + d] = f2bf(Wg[((size_t)t * D + d) * 8 + e]);
}

// ---------------- bf16 MFMA GEMM: C[M,N] = A[M,K](lda) * Bt[N,K]^T ----------
// 256x256 tile, 512 threads = 8 waves (2M x 4N), per-wave 128x64.
// 8-phase k-slab schedule, 4-slot LDS rotation, TRUE counted vmcnt.
__global__ __launch_bounds__(512, 2) void gemm256(
    const unsigned short* __restrict__ A, int lda,
    const unsigned short* __restrict__ Bt,
    unsigned short* __restrict__ C, int ldc, int K,
    size_t aStrideE, size_t bStrideE, size_t cStrideE,
    float* __restrict__ sum, float* __restrict__ sq,
    int statStrideE, int statCols, int groupM, int GN) {
  // 4 slots x (A 16KB | B 16KB) = 128 KiB
  __shared__ __attribute__((aligned(128))) char smem[131072];
  const int tid = threadIdx.x;
  const int lane = tid & 63;
  const int wid = tid >> 6;
  const int wm = wid & 1;           // 2 M-waves
  const int wn = wid >> 1;          // 4 N-waves
  const int e = blockIdx.z;

  int bx, by;
  if (groupM) {
    // XCD-bijective remap (grid.x % 8 == 0), then 16x16 group decode.
    int bid = blockIdx.x;
    int cpx = (int)gridDim.x >> 3;
    int b2 = (bid & 7) * cpx + (bid >> 3);
    int gsize = groupM * GN;
    int gid = b2 / gsize;
    int rem = b2 - gid * gsize;
    bx = gid * groupM + rem % groupM;
    by = rem / groupM;
  } else {
    bx = blockIdx.x; by = blockIdx.y;
  }

  const unsigned short* Ae = A + (size_t)e * aStrideE + (size_t)bx * 256 * lda;
  const unsigned short* Be = Bt + (size_t)e * bStrideE + (size_t)by * 256 * K;

  // staging: one 16KB half-slab per stage call = 2 x async16 per thread.
  // LDS dest linear: o = l*8192 + tid*16 -> row = l*128 + (tid>>2),
  // colbyte = (tid&3)*16.  Logical col = colbyte ^ (((row>>1)&3)<<4) ->
  // pre-swizzled SOURCE col (elems): 8*((tid&3) ^ ((tid>>3)&3)).
  const int srow = tid >> 2;                                  // 0..127
  const int scol = 8 * ((tid & 3) ^ ((tid >> 3) & 3));
  const unsigned short* gA = Ae + (size_t)srow * lda + scol;
  const unsigned short* gB = Be + (size_t)srow * K + scol;
  const size_t aRow128 = (size_t)128 * lda;
  const size_t bRow128 = (size_t)128 * K;
  char* ldsDst = smem + tid * 16;

  auto stageA = [&](int u) {
    char* d = ldsDst + (u & 3) * 32768;
    const unsigned short* g = gA + u * 32;
    async16(g, d);
    async16(g + aRow128, d + 8192);
  };
  auto stageB = [&](int u) {
    char* d = ldsDst + (u & 3) * 32768 + 16384;
    const unsigned short* g = gB + u * 32;
    async16(g, d);
    async16(g + bRow128, d + 8192);
  };

  // fragment reads: row = wm*128 + i*16 + mrow (A) / wn*64 + j*16 + mrow (B),
  // physical colbyte = ((lane>>4)<<4) ^ (((mrow>>1)&3)<<4).  Row stride 64B.
  const int mrow = lane & 15;
  const int kgb = ((lane >> 4) << 4) ^ (((mrow >> 1) & 3) << 4);
  const char* rdA = smem + (wm * 128 + mrow) * 64 + kgb;
  const char* rdB = smem + 16384 + (wn * 64 + mrow) * 64 + kgb;

  f32x4 acc[8][4] = {};
  const int NS = K >> 5;            // 32-wide k-slabs

  // slab body: 2 phases.  ih=0: read 4A+4B frags, stage A(u+2), barrier,
  // 16 MFMA, barrier.  ih=1: read 4 more A frags (B reused), stage B(u+2),
  // barrier, 16 MFMA.  End-of-slab wait/barrier handled by caller.
  auto slab = [&](int u, bool st) {
    const char* pa = rdA + (u & 3) * 32768;
    const char* pb = rdB + (u & 3) * 32768;
    bf16x8 af[4], bfr[4];
#pragma unroll
    for (int i = 0; i < 4; ++i) af[i] = *(const bf16x8*)(pa + i * 1024);
#pragma unroll
    for (int j = 0; j < 4; ++j) bfr[j] = *(const bf16x8*)(pb + j * 1024);
    if (st) stageA(u + 2);
    __builtin_amdgcn_s_barrier();
    __builtin_amdgcn_s_setprio(1);
#pragma unroll
    for (int i = 0; i < 4; ++i)
#pragma unroll
      for (int j = 0; j < 4; ++j)
        acc[i][j] = __builtin_amdgcn_mfma_f32_16x16x32_bf16(af[i], bfr[j], acc[i][j], 0, 0, 0);
    __builtin_amdgcn_s_setprio(0);
    __builtin_amdgcn_s_barrier();
#pragma unroll
    for (int i = 0; i < 4; ++i) af[i] = *(const bf16x8*)(pa + (i + 4) * 1024);
    if (st) stageB(u + 2);
    __builtin_amdgcn_s_barrier();
    __builtin_amdgcn_s_setprio(1);
#pragma unroll
    for (int i = 0; i < 4; ++i)
#pragma unroll
      for (int j = 0; j < 4; ++j)
        acc[i + 4][j] = __builtin_amdgcn_mfma_f32_16x16x32_bf16(af[i], bfr[j], acc[i + 4][j], 0, 0, 0);
    __builtin_amdgcn_s_setprio(0);
  };

  // prologue: slabs 0,1 staged; wait for slab 0 only (slab 1 stays in flight).
  stageA(0); stageB(0); stageA(1); stageB(1);
  asm volatile("s_waitcnt vmcnt(4)");
  __builtin_amdgcn_s_barrier();
  __builtin_amdgcn_sched_barrier(0);

  int u = 0;
  for (; u < NS - 2; ++u) {
    slab(u, true);
    // retire slab u+1's 4 loads/thread; leave slab u+2's 4 in flight.
    // Barrier makes residency global (each wave drains its own, rendezvous).
    asm volatile("s_waitcnt vmcnt(4)");
    __builtin_amdgcn_s_barrier();
    __builtin_amdgcn_sched_barrier(0);   // pin next slab's ds_reads below
  }
  slab(u, false); ++u;     // u = NS-2: nothing staged
  asm volatile("s_waitcnt vmcnt(0)");
  __builtin_amdgcn_s_barrier();
  __builtin_amdgcn_sched_barrier(0);
  slab(u, false);          // u = NS-1: final slab

  // C/D layout (verified m89/m91): col = lane&15, row = (lane>>4)*4 + reg
  unsigned short* Ce = C + (size_t)e * cStrideE + (size_t)bx * 256 * ldc +
                       (size_t)by * 256;
  const int r0 = wm * 128 + (lane >> 4) * 4;
  const int c0 = wn * 64 + mrow;
#pragma unroll
  for (int i = 0; i < 8; ++i)
#pragma unroll
    for (int j = 0; j < 4; ++j)
#pragma unroll
      for (int r = 0; r < 4; ++r)
        Ce[(size_t)(r0 + i * 16 + r) * ldc + c0 + j * 16] = f2bf(acc[i][j][r]);

  // column stats: lanes {l, l^16, l^32, l^48} share columns and cover all
  // 128 rows of this wave's half-tile; butterfly over lane>>4, then atomic.
  float* se = sum + (size_t)e * statStrideE;
  float* qe = sq + (size_t)e * statStrideE;
#pragma unroll
  for (int j = 0; j < 4; ++j) {
    float s = 0.f, q = 0.f;
#pragma unroll
    for (int i = 0; i < 8; ++i)
#pragma unroll
      for (int r = 0; r < 4; ++r) {
        float v = acc[i][j][r];
        s += v;
        q = fmaf(v, v, q);
      }
    s += __shfl_xor(s, 16, 64); s += __shfl_xor(s, 32, 64);
    q += __shfl_xor(q, 16, 64); q += __shfl_xor(q, 32, 64);
    if ((lane >> 4) == 0) {
      int col = by * 256 + wn * 64 + j * 16 + mrow;
      if (col < statCols) {
        atomicAdd(&se[col], s);
        atomicAdd(&qe[col], q);
      }
    }
  }
}

// ---------------- BN coefficients: y = a*x + c ------------------------------
__global__ void bn_coef(const float* __restrict__ sum, const float* __restrict__ sq,
                        const float* __restrict__ g, const float* __restrict__ be,
                        float* __restrict__ A, float* __restrict__ C, int n, float invB) {
  int i = blockIdx.x * blockDim.x + threadIdx.x;
  if (i < n) {
    float mean = sum[i] * invB;
    float var = sq[i] * invB - mean * mean;   // biased var, matches reference
    float a = g[i] * rsqrtf(var + 1e-5f);
    A[i] = a;
    C[i] = be[i] - mean * a;
  }
}

// ---------------- gate logits (bf16 MFMA) + softmax -> gates [T][B][8] ------
__global__ __launch_bounds__(256) void gates_mfma(
    const unsigned short* __restrict__ xb,   // [B][1472] bf16
    const unsigned short* __restrict__ wgt,  // [16][1472] bf16, row te=t*8+e
    const float* __restrict__ bg,            // [16]
    float* __restrict__ gates, int Bn) {
  const int lane = threadIdx.x & 63;
  const int w = threadIdx.x >> 6;
  const int row0 = blockIdx.x * 64 + w * 16;
  const int mrow = lane & 15, kseg = (lane >> 4) * 8;
  const unsigned short* pa = xb + (size_t)(row0 + mrow) * 1472 + kseg;
  const unsigned short* pb = wgt + (size_t)mrow * 1472 + kseg;
  f32x4 acc = {};
  bf16x8 a0 = *(const bf16x8*)pa, b0 = *(const bf16x8*)pb;
  for (int ks = 1; ks < 46; ++ks) {
    bf16x8 a1 = *(const bf16x8*)(pa + ks * 32);
    bf16x8 b1 = *(const bf16x8*)(pb + ks * 32);
    acc = __builtin_amdgcn_mfma_f32_16x16x32_bf16(a0, b0, acc, 0, 0, 0);
    a0 = a1; b0 = b1;
  }
  acc = __builtin_amdgcn_mfma_f32_16x16x32_bf16(a0, b0, acc, 0, 0, 0);
  // lane holds col c = lane&15 (= te), rows (lane>>4)*4 + r.
  const int c = lane & 15;
  const float bias = bg[c];
#pragma unroll
  for (int r = 0; r < 4; ++r) {
    float v = acc[r] + bias;
    float m = v;                                   // max over 8-expert half
    m = fmaxf(m, __shfl_xor(m, 1, 64));
    m = fmaxf(m, __shfl_xor(m, 2, 64));
    m = fmaxf(m, __shfl_xor(m, 4, 64));
    float p = expf(v - m);
    float s = p;
    s += __shfl_xor(s, 1, 64);
    s += __shfl_xor(s, 2, 64);
    s += __shfl_xor(s, 4, 64);
    int rowg = row0 + (lane >> 4) * 4 + r;
    gates[((size_t)(c >> 3) * Bn + rowg) * 8 + (c & 7)] = p / s;
  }
}

// ---------------- in-place BN+ReLU on bf16 h1[B][4096] ----------------------
__global__ void bn_relu_inplace(unsigned short* __restrict__ h, const float* __restrict__ A,
                                const float* __restrict__ C) {
  int tid = blockIdx.x * blockDim.x + threadIdx.x;   // one vec8 per thread
  int r = tid >> 9, cb = tid & 511;                  // 512 vec8 slots per row
  int col = cb * 8;
  size_t i = (size_t)r * 4096 + col;
  uint4 v = *(const uint4*)(h + i);
  unsigned int w[4] = {v.x, v.y, v.z, v.w};
#pragma unroll
  for (int j = 0; j < 4; ++j) {
    float f0 = __uint_as_float(w[j] << 16);
    float f1 = __uint_as_float(w[j] & 0xffff0000u);
    float y0 = fmaxf(fmaf(A[col + 2 * j], f0, C[col + 2 * j]), 0.f);
    float y1 = fmaxf(fmaf(A[col + 2 * j + 1], f1, C[col + 2 * j + 1]), 0.f);
    w[j] = (unsigned int)f2bf(y0) | ((unsigned int)f2bf(y1) << 16);
  }
  *(uint4*)(h + i) = make_uint4(w[0], w[1], w[2], w[3]);
}

// ---------------- BN2+ReLU+gate -> out [T][B][2048] -------------------------
__global__ void combine(const unsigned short* __restrict__ h2,   // [B][2048]
                        const float* __restrict__ A, const float* __restrict__ C,
                        const float* __restrict__ gates,          // [T][B][8]
                        float* __restrict__ out, int Bn) {
  int b = blockIdx.x;
  int c = threadIdx.x * 8;            // 256 threads x 8 = 2048 cols
  int e = c >> 8;
  uint4 v = *(const uint4*)(h2 + (size_t)b * 2048 + c);
  unsigned int w[4] = {v.x, v.y, v.z, v.w};
  float y[8];
#pragma unroll
  for (int j = 0; j < 4; ++j) {
    float f0 = __uint_as_float(w[j] << 16);
    float f1 = __uint_as_float(w[j] & 0xffff0000u);
    y[2 * j]     = fmaxf(fmaf(A[c + 2 * j], f0, C[c + 2 * j]), 0.f);
    y[2 * j + 1] = fmaxf(fmaf(A[c + 2 * j + 1], f1, C[c + 2 * j + 1]), 0.f);
  }
  float g0 = gates[(size_t)b * 8 + e];
  float g1 = gates[((size_t)Bn + b) * 8 + e];
  float4* o0 = (float4*)(out + (size_t)b * 2048 + c);
  float4* o1 = (float4*)(out + ((size_t)Bn + b) * 2048 + c);
  o0[0] = make_float4(y[0] * g0, y[1] * g0, y[2] * g0, y[3] * g0);
  o0[1] = make_float4(y[4] * g0, y[5] * g0, y[6] * g0, y[7] * g0);
  o1[0] = make_float4(y[0] * g1, y[1] * g1, y[2] * g1, y[3] * g1);
  o1[1] = make_float4(y[4] * g1, y[5] * g1, y[6] * g1, y[7] * g1);
}

// ---------------------------------------------------------------------------
extern "C" void kernel_launch(void* const* d_in, const int* in_sizes, int n_in,
                              void* d_out, int out_size, void* d_ws, size_t ws_size,
                              hipStream_t stream) {
  const int B = 32768, D = 1472, E = 8, H1 = 512, H2 = 256;
  const int N1 = E * H1;               // 4096 expert columns
  const float* x   = (const float*)d_in[0];
  const float* W1  = (const float*)d_in[1];
  // d_in[2] = b1 (cancels through BN), d_in[6] = b2 (cancels)
  const float* g1  = (const float*)d_in[3];
  const float* be1 = (const float*)d_in[4];
  const float* W2  = (const float*)d_in[5];
  const float* g2  = (const float*)d_in[7];
  const float* be2 = (const float*)d_in[8];
  const float* Wg  = (const float*)d_in[9];
  const float* bg  = (const float*)d_in[10];
  float* out = (float*)d_out;

  // workspace layout
  char* p = (char*)d_ws;
  unsigned short* x_b = (unsigned short*)p; p += (size_t)B * D * 2;          // 96.5 MB
  unsigned short* W1t = (unsigned short*)p; p += (size_t)N1 * D * 2;         // 12.1 MB
  unsigned short* Wgt = (unsigned short*)p; p += (size_t)16 * D * 2;         // 47 KB
  unsigned short* W2t = (unsigned short*)p; p += (size_t)E * H2 * H1 * 2;    //  2.1 MB
  unsigned short* h1b = (unsigned short*)p; p += (size_t)B * N1 * 2;         // 268 MB
  unsigned short* h2b = (unsigned short*)p; p += (size_t)B * E * H2 * 2;     // 134 MB
  float* gatesBuf = (float*)p; p += (size_t)2 * B * 8 * 4;                   //  2.1 MB
  float* sum1 = (float*)p; p += (size_t)N1 * 4;
  float* sq1  = (float*)p; p += (size_t)N1 * 4;
  float* sum2 = (float*)p; p += (size_t)E * H2 * 4;
  float* sq2  = (float*)p; p += (size_t)E * H2 * 4;
  float* A1   = (float*)p; p += (size_t)N1 * 4;
  float* C1   = (float*)p; p += (size_t)N1 * 4;
  float* A2   = (float*)p; p += (size_t)E * H2 * 4;
  float* C2   = (float*)p; p += (size_t)E * H2 * 4;

  // zero stats accumulators (sum1,sq1,sum2,sq2 contiguous)
  hipMemsetAsync(sum1, 0, (size_t)(2 * N1 + 2 * E * H2) * 4, stream);

  // prep
  convert_f32_bf16<<<(unsigned)((size_t)B * D / 1024), 256, 0, stream>>>(
      x, x_b, (size_t)B * D);
  transpose_bf16<<<dim3(D / 32, H1 / 32, E), dim3(32, 8), 0, stream>>>(W1, W1t, D, H1);
  transpose_wg<<<16 * D / 256, 256, 0, stream>>>(Wg, Wgt, D);
  transpose_bf16<<<dim3(H1 / 32, H2 / 32, E), dim3(32, 8), 0, stream>>>(W2, W2t, H1, H2);

  // GEMM1: h1[B][4096] = x_b[B][D] @ W1t[4096][D]^T
  // grid 2048 = 8 XCD chunks x (16x16) groups
  gemm256<<<dim3(128 * 16), 512, 0, stream>>>(
      x_b, D, W1t, h1b, N1, D, (size_t)0, (size_t)0, (size_t)0,
      sum1, sq1, 0, N1, /*groupM=*/16, /*GN=*/16);

  bn_coef<<<N1 / 256, 256, 0, stream>>>(sum1, sq1, g1, be1, A1, C1, N1, 1.f / B);
  gates_mfma<<<B / 64, 256, 0, stream>>>(x_b, Wgt, bg, gatesBuf, B);
  bn_relu_inplace<<<(unsigned)((size_t)B * 512 / 256), 256, 0, stream>>>(h1b, A1, C1);

  // GEMM2 per expert: h2[B][e*256..] = h1[B][e*512..](lda=4096) @ W2t[e]
  gemm256<<<dim3(B / 256, 1, E), 512, 0, stream>>>(
      h1b, N1, W2t, h2b, E * H2, H1,
      (size_t)H1, (size_t)H1 * H2, (size_t)H2,
      sum2, sq2, H2, H2, /*groupM=*/0, /*GN=*/0);

  bn_coef<<<E * H2 / 256, 256, 0, stream>>>(sum2, sq2, g2, be2, A2, C2, E * H2, 1.f / B);

  // BN2 + ReLU + gate + write output
  combine<<<B, 256, 0, stream>>>(h2b, A2, C2, gatesBuf, out, B);
}

// Round 4
// 1350.534 us; speedup vs baseline: 1.0797x; 1.0797x over previous
//
#include <hip/hip_runtime.h>
#include <cstdint>

// ---------------------------------------------------------------------------
// MMoE: x[B,D] -> E experts (Linear D->H1, BN+ReLU, Linear H1->H2, BN+ReLU),
// T gates (softmax over E), out[t,b,e*H2+k] = expert[e,b,k]*gate[t,b,e].
// B=32768 D=1472 E=8 H1=512 H2=256 T=2.
//
// R6 structure (this round):
//  - GEMM1 (gemm256): unchanged from R5 (256x256 tile, 8-phase k-slab,
//    4-slot LDS rotation, counted vmcnt, XOR swizzle, setprio, fused stats).
//    Three schedule variants measured 43-45% MfmaUtil -> schedule is not the
//    binding constraint at 1 block/CU (248 unified regs); left alone.
//  - NEW gemm2_fused: BN1+ReLU fused into GEMM2's A-staging.  A is
//    reg-staged (global_load_dwordx4 -> fma/max/f2bf -> ds_write_b128, same
//    math as the old bn_relu_inplace -> bitwise-identical A operands);
//    B (W2t, L2-hot) stays on async global_load_lds.  2-slot double buffer,
//    __syncthreads per slab (compiler-managed waits; 16 slabs only).
//    Deletes bn_relu_inplace entirely: h1 traffic 1072 MB -> 536 MB.
//  - Gates: tiny MFMA kernel from x_b (L3-resident).  h1 is [B][4096] pre-BN;
//    gemm2_fused reads expert slice in place (lda=4096).
//  - Biases b1/b2 cancel exactly through BatchNorm -> skipped.
// ---------------------------------------------------------------------------

typedef __attribute__((ext_vector_type(8))) __bf16 bf16x8;
typedef __attribute__((ext_vector_type(4))) float f32x4;

__device__ __forceinline__ unsigned short f2bf(float f) {
  unsigned int u = __float_as_uint(f);
  u += 0x7fffu + ((u >> 16) & 1u);   // round-to-nearest-even
  return (unsigned short)(u >> 16);
}

// async global->LDS, 16B per lane.  LDS dest must be wave-uniform base + lane*16.
__device__ __forceinline__ void async16(const void* g, void* l) {
  __builtin_amdgcn_global_load_lds((__attribute__((address_space(1))) unsigned int*)g,
                                   (__attribute__((address_space(3))) unsigned int*)l,
                                   16, 0, 0);
}

// ---------------- fp32 -> bf16 elementwise convert (x) ----------------------
__global__ void convert_f32_bf16(const float* __restrict__ in,
                                 unsigned short* __restrict__ out, size_t n) {
  size_t i = ((size_t)blockIdx.x * blockDim.x + threadIdx.x) * 4;
  if (i + 3 < n) {
    float4 v = *(const float4*)(in + i);
    unsigned int w0 = (unsigned int)f2bf(v.x) | ((unsigned int)f2bf(v.y) << 16);
    unsigned int w1 = (unsigned int)f2bf(v.z) | ((unsigned int)f2bf(v.w) << 16);
    *(uint2*)(out + i) = make_uint2(w0, w1);
  }
}

// ---------------- W[E][D][H] fp32 -> Wt rows [e*H+h][D] bf16 ----------------
__global__ void transpose_bf16(const float* __restrict__ W,
                               unsigned short* __restrict__ Wt, int D, int H) {
  __shared__ float tile[32][33];
  int e = blockIdx.z;
  int d0 = blockIdx.x * 32, h0 = blockIdx.y * 32;
  const float* We = W + (size_t)e * D * H;
  unsigned short* Wte = Wt + (size_t)e * D * H;
  int tx = threadIdx.x, ty = threadIdx.y;  // block (32,8)
#pragma unroll
  for (int i = 0; i < 4; ++i)
    tile[ty + i * 8][tx] = We[(size_t)(d0 + ty + i * 8) * H + h0 + tx];
  __syncthreads();
#pragma unroll
  for (int i = 0; i < 4; ++i)
    Wte[(size_t)(h0 + ty + i * 8) * D + d0 + tx] = f2bf(tile[tx][ty + i * 8]);
}

// ---------------- Wg[T][D][E] fp32 -> rows [t*8+e][D] bf16 ------------------
__global__ void transpose_wg(const float* __restrict__ Wg,
                             unsigned short* __restrict__ Wt, int D) {
  int idx = blockIdx.x * 256 + threadIdx.x;            // 16*D total
  int te = idx / D, d = idx - te * D;
  int t = te >> 3, e = te & 7;
  Wt[(size_t)te * D + d] = f2bf(Wg[((size_t)t * D + d) * 8 + e]);
}

// ---------------- bf16 MFMA GEMM1: C[M,N] = A[M,K](lda) * Bt[N,K]^T ---------
// 256x256 tile, 512 threads = 8 waves (2M x 4N), per-wave 128x64.
// 8-phase k-slab schedule, 4-slot LDS rotation, counted vmcnt.
__global__ __launch_bounds__(512, 2) void gemm256(
    const unsigned short* __restrict__ A, int lda,
    const unsigned short* __restrict__ Bt,
    unsigned short* __restrict__ C, int ldc, int K,
    float* __restrict__ sum, float* __restrict__ sq,
    int statCols, int groupM, int GN) {
  // 4 slots x (A 16KB | B 16KB) = 128 KiB
  __shared__ __attribute__((aligned(128))) char smem[131072];
  const int tid = threadIdx.x;
  const int lane = tid & 63;
  const int wid = tid >> 6;
  const int wm = wid & 1;           // 2 M-waves
  const int wn = wid >> 1;          // 4 N-waves

  // XCD-bijective remap (grid.x % 8 == 0), then groupM x GN group decode.
  int bid = blockIdx.x;
  int cpx = (int)gridDim.x >> 3;
  int b2 = (bid & 7) * cpx + (bid >> 3);
  int gsize = groupM * GN;
  int gid = b2 / gsize;
  int rem = b2 - gid * gsize;
  int bx = gid * groupM + rem % groupM;
  int by = rem / groupM;

  const unsigned short* Ae = A + (size_t)bx * 256 * lda;
  const unsigned short* Be = Bt + (size_t)by * 256 * K;

  // staging: one 16KB half-slab per stage call = 2 x async16 per thread.
  // LDS dest linear: row = l*128 + (tid>>2), colbyte = (tid&3)*16.
  // Logical col = colbyte ^ (((row>>1)&3)<<4) -> pre-swizzled SOURCE col.
  const int srow = tid >> 2;                                  // 0..127
  const int scol = 8 * ((tid & 3) ^ ((tid >> 3) & 3));
  const unsigned short* gA = Ae + (size_t)srow * lda + scol;
  const unsigned short* gB = Be + (size_t)srow * K + scol;
  const size_t aRow128 = (size_t)128 * lda;
  const size_t bRow128 = (size_t)128 * K;
  char* ldsDst = smem + tid * 16;

  auto stageA = [&](int u) {
    char* d = ldsDst + (u & 3) * 32768;
    const unsigned short* g = gA + u * 32;
    async16(g, d);
    async16(g + aRow128, d + 8192);
  };
  auto stageB = [&](int u) {
    char* d = ldsDst + (u & 3) * 32768 + 16384;
    const unsigned short* g = gB + u * 32;
    async16(g, d);
    async16(g + bRow128, d + 8192);
  };

  // fragment reads: row = wm*128 + i*16 + mrow (A) / wn*64 + j*16 + mrow (B),
  // physical colbyte = ((lane>>4)<<4) ^ (((mrow>>1)&3)<<4).  Row stride 64B.
  const int mrow = lane & 15;
  const int kgb = ((lane >> 4) << 4) ^ (((mrow >> 1) & 3) << 4);
  const char* rdA = smem + (wm * 128 + mrow) * 64 + kgb;
  const char* rdB = smem + 16384 + (wn * 64 + mrow) * 64 + kgb;

  f32x4 acc[8][4] = {};
  const int NS = K >> 5;            // 32-wide k-slabs

  auto slab = [&](int u, bool st) {
    const char* pa = rdA + (u & 3) * 32768;
    const char* pb = rdB + (u & 3) * 32768;
    bf16x8 af[4], bfr[4];
#pragma unroll
    for (int i = 0; i < 4; ++i) af[i] = *(const bf16x8*)(pa + i * 1024);
#pragma unroll
    for (int j = 0; j < 4; ++j) bfr[j] = *(const bf16x8*)(pb + j * 1024);
    if (st) stageA(u + 2);
    __builtin_amdgcn_s_barrier();
    __builtin_amdgcn_s_setprio(1);
#pragma unroll
    for (int i = 0; i < 4; ++i)
#pragma unroll
      for (int j = 0; j < 4; ++j)
        acc[i][j] = __builtin_amdgcn_mfma_f32_16x16x32_bf16(af[i], bfr[j], acc[i][j], 0, 0, 0);
    __builtin_amdgcn_s_setprio(0);
    __builtin_amdgcn_s_barrier();
#pragma unroll
    for (int i = 0; i < 4; ++i) af[i] = *(const bf16x8*)(pa + (i + 4) * 1024);
    if (st) stageB(u + 2);
    __builtin_amdgcn_s_barrier();
    __builtin_amdgcn_s_setprio(1);
#pragma unroll
    for (int i = 0; i < 4; ++i)
#pragma unroll
      for (int j = 0; j < 4; ++j)
        acc[i + 4][j] = __builtin_amdgcn_mfma_f32_16x16x32_bf16(af[i], bfr[j], acc[i + 4][j], 0, 0, 0);
    __builtin_amdgcn_s_setprio(0);
  };

  // prologue: slabs 0,1 staged; wait for slab 0 only (slab 1 stays in flight).
  stageA(0); stageB(0); stageA(1); stageB(1);
  asm volatile("s_waitcnt vmcnt(4)");
  __builtin_amdgcn_s_barrier();
  __builtin_amdgcn_sched_barrier(0);

  int u = 0;
  for (; u < NS - 2; ++u) {
    slab(u, true);
    // retire slab u+1's 4 loads/thread; leave slab u+2's 4 in flight.
    asm volatile("s_waitcnt vmcnt(4)");
    __builtin_amdgcn_s_barrier();
    __builtin_amdgcn_sched_barrier(0);   // pin next slab's ds_reads below
  }
  slab(u, false); ++u;     // u = NS-2: nothing staged
  asm volatile("s_waitcnt vmcnt(0)");
  __builtin_amdgcn_s_barrier();
  __builtin_amdgcn_sched_barrier(0);
  slab(u, false);          // u = NS-1: final slab

  // C/D layout (verified m89/m91): col = lane&15, row = (lane>>4)*4 + reg
  unsigned short* Ce = C + (size_t)bx * 256 * ldc + (size_t)by * 256;
  const int r0 = wm * 128 + (lane >> 4) * 4;
  const int c0 = wn * 64 + mrow;
#pragma unroll
  for (int i = 0; i < 8; ++i)
#pragma unroll
    for (int j = 0; j < 4; ++j)
#pragma unroll
      for (int r = 0; r < 4; ++r)
        Ce[(size_t)(r0 + i * 16 + r) * ldc + c0 + j * 16] = f2bf(acc[i][j][r]);

  // column stats: butterfly over lane>>4, then atomic.
#pragma unroll
  for (int j = 0; j < 4; ++j) {
    float s = 0.f, q = 0.f;
#pragma unroll
    for (int i = 0; i < 8; ++i)
#pragma unroll
      for (int r = 0; r < 4; ++r) {
        float v = acc[i][j][r];
        s += v;
        q = fmaf(v, v, q);
      }
    s += __shfl_xor(s, 16, 64); s += __shfl_xor(s, 32, 64);
    q += __shfl_xor(q, 16, 64); q += __shfl_xor(q, 32, 64);
    if ((lane >> 4) == 0) {
      int col = by * 256 + wn * 64 + j * 16 + mrow;
      if (col < statCols) {
        atomicAdd(&sum[col], s);
        atomicAdd(&sq[col], q);
      }
    }
  }
}

// ---------------- GEMM2 with fused BN1+ReLU on the A path -------------------
// h2[bx*256.., e*256..] = BN1ReLU(h1[bx*256.., e*512..]) @ W2t[e]^T.
// 256x256 tile (full expert width), K=512 -> 16 slabs.  A: reg-staged with
// the exact bn_relu math (bitwise-identical to the old separate pass);
// B: async16.  2-slot double buffer, __syncthreads per slab.
__global__ __launch_bounds__(512) void gemm2_fused(
    const unsigned short* __restrict__ H1,   // [B][4096] pre-BN bf16
    const float* __restrict__ A1, const float* __restrict__ C1,  // [4096]
    const unsigned short* __restrict__ W2t,  // [E][256][512] bf16
    unsigned short* __restrict__ H2,         // [B][2048] bf16
    float* __restrict__ sum, float* __restrict__ sq) {  // [E*256]
  __shared__ __attribute__((aligned(128))) char smem[2][32768];
  const int tid = threadIdx.x;
  const int lane = tid & 63;
  const int wid = tid >> 6;
  const int wm = wid & 1;           // 2 M-waves
  const int wn = wid >> 1;          // 4 N-waves
  const int e = blockIdx.z;
  const int bx = blockIdx.x;

  const unsigned short* Ae = H1 + (size_t)bx * 256 * 4096 + e * 512;
  const unsigned short* Be = W2t + (size_t)e * 256 * 512;

  const int srow = tid >> 2;                                  // 0..127
  const int scol = 8 * ((tid & 3) ^ ((tid >> 3) & 3));        // pre-swizzled col
  const unsigned short* gA = Ae + (size_t)srow * 4096 + scol;
  const unsigned short* gB = Be + (size_t)srow * 512 + scol;
  const size_t aRow128 = (size_t)128 * 4096;
  const size_t bRow128 = (size_t)128 * 512;
  const float* a1p = A1 + e * 512 + scol;
  const float* c1p = C1 + e * 512 + scol;

  // BN1+ReLU on 8 bf16 (same ops as the old bn_relu_inplace -> bitwise-same)
  auto bnrelu = [&](uint4 v, int kc) -> uint4 {
    unsigned int w[4] = {v.x, v.y, v.z, v.w};
    unsigned int o[4];
#pragma unroll
    for (int j = 0; j < 4; ++j) {
      float f0 = __uint_as_float(w[j] << 16);
      float f1 = __uint_as_float(w[j] & 0xffff0000u);
      float y0 = fmaxf(fmaf(a1p[kc + 2 * j], f0, c1p[kc + 2 * j]), 0.f);
      float y1 = fmaxf(fmaf(a1p[kc + 2 * j + 1], f1, c1p[kc + 2 * j + 1]), 0.f);
      o[j] = (unsigned int)f2bf(y0) | ((unsigned int)f2bf(y1) << 16);
    }
    return make_uint4(o[0], o[1], o[2], o[3]);
  };

  const int mrow = lane & 15;
  const int kgb = ((lane >> 4) << 4) ^ (((mrow >> 1) & 3) << 4);
  const int rdAo = (wm * 128 + mrow) * 64 + kgb;
  const int rdBo = 16384 + (wn * 64 + mrow) * 64 + kgb;

  f32x4 acc[8][4] = {};

  // prologue: slab 0 into slot 0
  {
    uint4 va0 = *(const uint4*)(gA);
    uint4 va1 = *(const uint4*)(gA + aRow128);
    async16(gB, smem[0] + tid * 16 + 16384);
    async16(gB + bRow128, smem[0] + tid * 16 + 16384 + 8192);
    uint4 t0 = bnrelu(va0, 0), t1 = bnrelu(va1, 0);
    *(uint4*)(smem[0] + tid * 16) = t0;
    *(uint4*)(smem[0] + tid * 16 + 8192) = t1;
  }
  __syncthreads();

  for (int u = 0; u < 16; ++u) {
    const int slot = u & 1, nslot = slot ^ 1;
    uint4 va0, va1;
    if (u < 15) {
      va0 = *(const uint4*)(gA + (u + 1) * 32);
      va1 = *(const uint4*)(gA + (u + 1) * 32 + aRow128);
      async16(gB + (u + 1) * 32, smem[nslot] + tid * 16 + 16384);
      async16(gB + (u + 1) * 32 + bRow128, smem[nslot] + tid * 16 + 16384 + 8192);
    }
    // compute slab u from smem[slot]
    {
      const char* pa = smem[slot] + rdAo;
      const char* pb = smem[slot] + rdBo;
      bf16x8 af[8], bfr[4];
#pragma unroll
      for (int i = 0; i < 8; ++i) af[i] = *(const bf16x8*)(pa + i * 1024);
#pragma unroll
      for (int j = 0; j < 4; ++j) bfr[j] = *(const bf16x8*)(pb + j * 1024);
      __builtin_amdgcn_s_setprio(1);
#pragma unroll
      for (int i = 0; i < 8; ++i)
#pragma unroll
        for (int j = 0; j < 4; ++j)
          acc[i][j] = __builtin_amdgcn_mfma_f32_16x16x32_bf16(af[i], bfr[j], acc[i][j], 0, 0, 0);
      __builtin_amdgcn_s_setprio(0);
    }
    if (u < 15) {
      uint4 t0 = bnrelu(va0, (u + 1) * 32);
      uint4 t1 = bnrelu(va1, (u + 1) * 32);
      *(uint4*)(smem[nslot] + tid * 16) = t0;
      *(uint4*)(smem[nslot] + tid * 16 + 8192) = t1;
    }
    __syncthreads();   // drains async16 (vmcnt) + ds_writes (lgkm)
  }

  // epilogue: C-write + stats (statCols = 256, ldc = 2048)
  unsigned short* Ce = H2 + (size_t)bx * 256 * 2048 + e * 256;
  const int r0 = wm * 128 + (lane >> 4) * 4;
  const int c0 = wn * 64 + mrow;
#pragma unroll
  for (int i = 0; i < 8; ++i)
#pragma unroll
    for (int j = 0; j < 4; ++j)
#pragma unroll
      for (int r = 0; r < 4; ++r)
        Ce[(size_t)(r0 + i * 16 + r) * 2048 + c0 + j * 16] = f2bf(acc[i][j][r]);

  float* se = sum + (size_t)e * 256;
  float* qe = sq + (size_t)e * 256;
#pragma unroll
  for (int j = 0; j < 4; ++j) {
    float s = 0.f, q = 0.f;
#pragma unroll
    for (int i = 0; i < 8; ++i)
#pragma unroll
      for (int r = 0; r < 4; ++r) {
        float v = acc[i][j][r];
        s += v;
        q = fmaf(v, v, q);
      }
    s += __shfl_xor(s, 16, 64); s += __shfl_xor(s, 32, 64);
    q += __shfl_xor(q, 16, 64); q += __shfl_xor(q, 32, 64);
    if ((lane >> 4) == 0) {
      int col = wn * 64 + j * 16 + mrow;
      atomicAdd(&se[col], s);
      atomicAdd(&qe[col], q);
    }
  }
}

// ---------------- BN coefficients: y = a*x + c ------------------------------
__global__ void bn_coef(const float* __restrict__ sum, const float* __restrict__ sq,
                        const float* __restrict__ g, const float* __restrict__ be,
                        float* __restrict__ A, float* __restrict__ C, int n, float invB) {
  int i = blockIdx.x * blockDim.x + threadIdx.x;
  if (i < n) {
    float mean = sum[i] * invB;
    float var = sq[i] * invB - mean * mean;   // biased var, matches reference
    float a = g[i] * rsqrtf(var + 1e-5f);
    A[i] = a;
    C[i] = be[i] - mean * a;
  }
}

// ---------------- gate logits (bf16 MFMA) + softmax -> gates [T][B][8] ------
__global__ __launch_bounds__(256) void gates_mfma(
    const unsigned short* __restrict__ xb,   // [B][1472] bf16
    const unsigned short* __restrict__ wgt,  // [16][1472] bf16, row te=t*8+e
    const float* __restrict__ bg,            // [16]
    float* __restrict__ gates, int Bn) {
  const int lane = threadIdx.x & 63;
  const int w = threadIdx.x >> 6;
  const int row0 = blockIdx.x * 64 + w * 16;
  const int mrow = lane & 15, kseg = (lane >> 4) * 8;
  const unsigned short* pa = xb + (size_t)(row0 + mrow) * 1472 + kseg;
  const unsigned short* pb = wgt + (size_t)mrow * 1472 + kseg;
  f32x4 acc = {};
  bf16x8 a0 = *(const bf16x8*)pa, b0 = *(const bf16x8*)pb;
  for (int ks = 1; ks < 46; ++ks) {
    bf16x8 a1 = *(const bf16x8*)(pa + ks * 32);
    bf16x8 b1 = *(const bf16x8*)(pb + ks * 32);
    acc = __builtin_amdgcn_mfma_f32_16x16x32_bf16(a0, b0, acc, 0, 0, 0);
    a0 = a1; b0 = b1;
  }
  acc = __builtin_amdgcn_mfma_f32_16x16x32_bf16(a0, b0, acc, 0, 0, 0);
  // lane holds col c = lane&15 (= te), rows (lane>>4)*4 + r.
  const int c = lane & 15;
  const float bias = bg[c];
#pragma unroll
  for (int r = 0; r < 4; ++r) {
    float v = acc[r] + bias;
    float m = v;                                   // max over 8-expert half
    m = fmaxf(m, __shfl_xor(m, 1, 64));
    m = fmaxf(m, __shfl_xor(m, 2, 64));
    m = fmaxf(m, __shfl_xor(m, 4, 64));
    float p = expf(v - m);
    float s = p;
    s += __shfl_xor(s, 1, 64);
    s += __shfl_xor(s, 2, 64);
    s += __shfl_xor(s, 4, 64);
    int rowg = row0 + (lane >> 4) * 4 + r;
    gates[((size_t)(c >> 3) * Bn + rowg) * 8 + (c & 7)] = p / s;
  }
}

// ---------------- BN2+ReLU+gate -> out [T][B][2048] -------------------------
__global__ void combine(const unsigned short* __restrict__ h2,   // [B][2048]
                        const float* __restrict__ A, const float* __restrict__ C,
                        const float* __restrict__ gates,          // [T][B][8]
                        float* __restrict__ out, int Bn) {
  int b = blockIdx.x;
  int c = threadIdx.x * 8;            // 256 threads x 8 = 2048 cols
  int e = c >> 8;
  uint4 v = *(const uint4*)(h2 + (size_t)b * 2048 + c);
  unsigned int w[4] = {v.x, v.y, v.z, v.w};
  float y[8];
#pragma unroll
  for (int j = 0; j < 4; ++j) {
    float f0 = __uint_as_float(w[j] << 16);
    float f1 = __uint_as_float(w[j] & 0xffff0000u);
    y[2 * j]     = fmaxf(fmaf(A[c + 2 * j], f0, C[c + 2 * j]), 0.f);
    y[2 * j + 1] = fmaxf(fmaf(A[c + 2 * j + 1], f1, C[c + 2 * j + 1]), 0.f);
  }
  float g0 = gates[(size_t)b * 8 + e];
  float g1 = gates[((size_t)Bn + b) * 8 + e];
  float4* o0 = (float4*)(out + (size_t)b * 2048 + c);
  float4* o1 = (float4*)(out + ((size_t)Bn + b) * 2048 + c);
  o0[0] = make_float4(y[0] * g0, y[1] * g0, y[2] * g0, y[3] * g0);
  o0[1] = make_float4(y[4] * g0, y[5] * g0, y[6] * g0, y[7] * g0);
  o1[0] = make_float4(y[0] * g1, y[1] * g1, y[2] * g1, y[3] * g1);
  o1[1] = make_float4(y[4] * g1, y[5] * g1, y[6] * g1, y[7] * g1);
}

// ---------------------------------------------------------------------------
extern "C" void kernel_launch(void* const* d_in, const int* in_sizes, int n_in,
                              void* d_out, int out_size, void* d_ws, size_t ws_size,
                              hipStream_t stream) {
  const int B = 32768, D = 1472, E = 8, H1 = 512, H2 = 256;
  const int N1 = E * H1;               // 4096 expert columns
  const float* x   = (const float*)d_in[0];
  const float* W1  = (const float*)d_in[1];
  // d_in[2] = b1 (cancels through BN), d_in[6] = b2 (cancels)
  const float* g1  = (const float*)d_in[3];
  const float* be1 = (const float*)d_in[4];
  const float* W2  = (const float*)d_in[5];
  const float* g2  = (const float*)d_in[7];
  const float* be2 = (const float*)d_in[8];
  const float* Wg  = (const float*)d_in[9];
  const float* bg  = (const float*)d_in[10];
  float* out = (float*)d_out;

  // workspace layout
  char* p = (char*)d_ws;
  unsigned short* x_b = (unsigned short*)p; p += (size_t)B * D * 2;          // 96.5 MB
  unsigned short* W1t = (unsigned short*)p; p += (size_t)N1 * D * 2;         // 12.1 MB
  unsigned short* Wgt = (unsigned short*)p; p += (size_t)16 * D * 2;         // 47 KB
  unsigned short* W2t = (unsigned short*)p; p += (size_t)E * H2 * H1 * 2;    //  2.1 MB
  unsigned short* h1b = (unsigned short*)p; p += (size_t)B * N1 * 2;         // 268 MB
  unsigned short* h2b = (unsigned short*)p; p += (size_t)B * E * H2 * 2;     // 134 MB
  float* gatesBuf = (float*)p; p += (size_t)2 * B * 8 * 4;                   //  2.1 MB
  float* sum1 = (float*)p; p += (size_t)N1 * 4;
  float* sq1  = (float*)p; p += (size_t)N1 * 4;
  float* sum2 = (float*)p; p += (size_t)E * H2 * 4;
  float* sq2  = (float*)p; p += (size_t)E * H2 * 4;
  float* A1   = (float*)p; p += (size_t)N1 * 4;
  float* C1   = (float*)p; p += (size_t)N1 * 4;
  float* A2   = (float*)p; p += (size_t)E * H2 * 4;
  float* C2   = (float*)p; p += (size_t)E * H2 * 4;

  // zero stats accumulators (sum1,sq1,sum2,sq2 contiguous)
  hipMemsetAsync(sum1, 0, (size_t)(2 * N1 + 2 * E * H2) * 4, stream);

  // prep
  convert_f32_bf16<<<(unsigned)((size_t)B * D / 1024), 256, 0, stream>>>(
      x, x_b, (size_t)B * D);
  transpose_bf16<<<dim3(D / 32, H1 / 32, E), dim3(32, 8), 0, stream>>>(W1, W1t, D, H1);
  transpose_wg<<<16 * D / 256, 256, 0, stream>>>(Wg, Wgt, D);
  transpose_bf16<<<dim3(H1 / 32, H2 / 32, E), dim3(32, 8), 0, stream>>>(W2, W2t, H1, H2);

  // GEMM1: h1[B][4096] = x_b[B][D] @ W1t[4096][D]^T
  // grid 2048 = 8 XCD chunks x (16x16) groups
  gemm256<<<dim3(128 * 16), 512, 0, stream>>>(
      x_b, D, W1t, h1b, N1, D, sum1, sq1, N1, /*groupM=*/16, /*GN=*/16);

  bn_coef<<<N1 / 256, 256, 0, stream>>>(sum1, sq1, g1, be1, A1, C1, N1, 1.f / B);
  gates_mfma<<<B / 64, 256, 0, stream>>>(x_b, Wgt, bg, gatesBuf, B);

  // GEMM2 with fused BN1+ReLU: h2[B][e*256..] = BN1ReLU(h1[B][e*512..]) @ W2t[e]
  gemm2_fused<<<dim3(B / 256, 1, E), 512, 0, stream>>>(
      h1b, A1, C1, W2t, h2b, sum2, sq2);

  bn_coef<<<E * H2 / 256, 256, 0, stream>>>(sum2, sq2, g2, be2, A2, C2, E * H2, 1.f / B);

  // BN2 + ReLU + gate + write output
  combine<<<B, 256, 0, stream>>>(h2b, A2, C2, gatesBuf, out, B);
}